// Round 8
// baseline (319.737 us; speedup 1.0000x reference)
//
#include <hip/hip_runtime.h>
#include <hip/hip_bf16.h>
#include <math.h>

#define N_TOKENS 32768
#define HIDDEN   2048
#define NEXP     8
#define H4       (HIDDEN / 4)            // 512 float4 per row
#define BLOCK    256                     // 4 waves
#define WPB      (BLOCK / 64)
#define TOK_PER_WAVE 4
#define GRID     (N_TOKENS / (WPB * TOK_PER_WAVE))   // 2048 blocks = 8/CU

#define SCORES_OFF 0
#define IDX_OFF    (N_TOKENS * 2)        // 65536
#define HIST_OFF   (N_TOKENS * 4)        // 131072

__global__ void zero_hist_kernel(float* out) {
    if (threadIdx.x < NEXP) out[HIST_OFF + threadIdx.x] = 0.0f;
}

// top-2 with lowest-index tie-break (strict >), matching jax.lax.top_k.
// cnt: packed 4-bit per-expert counters (max 4 tokens/wave -> fits).
__device__ __forceinline__ void emit_token(const double* acc, int t,
                                           float* __restrict__ out, unsigned* cnt) {
    double b1 = acc[0]; int i1 = 0;
    double b2 = -1.0e300; int i2 = 0;
#pragma unroll
    for (int e = 1; e < NEXP; ++e) {
        double v = acc[e];
        if (v > b1)      { b2 = b1; i2 = i1; b1 = v; i1 = e; }
        else if (v > b2) { b2 = v;  i2 = e; }
    }
    float d  = (float)(b2 - b1);
    float e1 = expf(d);
    float s0 = 1.0f / (1.0f + e1);

    float2 sc; sc.x = s0; sc.y = e1 * s0;
    float2 ix; ix.x = (float)i1; ix.y = (float)i2;
    *reinterpret_cast<float2*>(out + SCORES_OFF + 2 * t) = sc;
    *reinterpret_cast<float2*>(out + IDX_OFF    + 2 * t) = ix;

    *cnt += (1u << (4 * i1)) + (1u << (4 * i2));
}

// Round-7 minus the W LDS staging: W (64 KB, read-hot) is served by L1/L2
// directly, removing 32 MB of per-block HBM re-fetch, ~50% LDS-pipe duty,
// and the staging barrier. e-loop at unroll 1 keeps live set ~60 < the
// 64-VGPR budget (x 16 + acc 32 + W 8). Numerics byte-identical to r7.
__global__ __launch_bounds__(BLOCK, 8) void router_kernel(
        const float* __restrict__ x, const float* __restrict__ W,
        float* __restrict__ out) {
    __shared__ float h[NEXP];

    const int tid  = threadIdx.x;
    const int wave = tid >> 6;
    const int lane = tid & 63;
    const int gw   = blockIdx.x * WPB + wave;

    if (tid < NEXP) h[tid] = 0.0f;
    __syncthreads();

    const float4* Wv = reinterpret_cast<const float4*>(W);
    unsigned cnt = 0;

#pragma unroll 1
    for (int p = 0; p < TOK_PER_WAVE / 2; ++p) {
        const int t0 = gw * TOK_PER_WAVE + 2 * p;
        const float4* xa = reinterpret_cast<const float4*>(x) + (size_t)t0 * H4;
        const float4* xb = xa + H4;

        // acc[0..7] = token a, acc[8..15] = token b
        double acc[16];
#pragma unroll
        for (int e = 0; e < 16; ++e) acc[e] = 0.0;

#pragma unroll 1
        for (int k = 0; k < 8; k += 2) {     // 4 iterations, 8-elem dot groups
            const float4 a0 = xa[lane + k * 64];
            const float4 a1 = xa[lane + (k + 1) * 64];
            const float4 b0 = xb[lane + k * 64];
            const float4 b1 = xb[lane + (k + 1) * 64];
#pragma unroll 1
            for (int e = 0; e < NEXP; ++e) {
                const float4 w0 = Wv[e * H4 + lane + k * 64];        // L1/L2 hit
                const float4 w1 = Wv[e * H4 + lane + (k + 1) * 64];
                float s0 = w0.x * a0.x;
                s0 = fmaf(w0.y, a0.y, s0); s0 = fmaf(w0.z, a0.z, s0); s0 = fmaf(w0.w, a0.w, s0);
                float s1 = w0.x * b0.x;
                s1 = fmaf(w0.y, b0.y, s1); s1 = fmaf(w0.z, b0.z, s1); s1 = fmaf(w0.w, b0.w, s1);
                s0 = fmaf(w1.x, a1.x, s0); s0 = fmaf(w1.y, a1.y, s0);
                s0 = fmaf(w1.z, a1.z, s0); s0 = fmaf(w1.w, a1.w, s0);
                s1 = fmaf(w1.x, b1.x, s1); s1 = fmaf(w1.y, b1.y, s1);
                s1 = fmaf(w1.z, b1.z, s1); s1 = fmaf(w1.w, b1.w, s1);
                acc[e]     += (double)s0;    // one f64 accumulate per 8 elems
                acc[8 + e] += (double)s1;
            }
        }

        // reduce-scatter butterfly (verified r6/r7): masks 1,2,4,8 halve
        // 16 values/lane -> 1, then 16,32 finish. Bit-identical totals to
        // the full butterfly (same pairing, commutative adds).
        {
            const bool u1 = lane & 1;
#pragma unroll
            for (int i = 0; i < 8; ++i) {
                double send = u1 ? acc[i] : acc[8 + i];
                double got  = __shfl_xor(send, 1, 64);
                acc[i] = (u1 ? acc[8 + i] : acc[i]) + got;
            }
            const bool u2 = lane & 2;
#pragma unroll
            for (int i = 0; i < 4; ++i) {
                double send = u2 ? acc[i] : acc[4 + i];
                double got  = __shfl_xor(send, 2, 64);
                acc[i] = (u2 ? acc[4 + i] : acc[i]) + got;
            }
            const bool u4 = lane & 4;
#pragma unroll
            for (int i = 0; i < 2; ++i) {
                double send = u4 ? acc[i] : acc[2 + i];
                double got  = __shfl_xor(send, 4, 64);
                acc[i] = (u4 ? acc[2 + i] : acc[i]) + got;
            }
            const bool u8 = lane & 8;
            {
                double send = u8 ? acc[0] : acc[1];
                double got  = __shfl_xor(send, 8, 64);
                acc[0] = (u8 ? acc[1] : acc[0]) + got;
            }
            acc[0] += __shfl_xor(acc[0], 16, 64);
            acc[0] += __shfl_xor(acc[0], 32, 64);
        }
        // value j sits at lane bitrev4(j): token a (j=e) at r, token b at r+1
        double v0[NEXP], v1[NEXP];
#pragma unroll
        for (int e = 0; e < NEXP; ++e) {
            const int r = ((e & 1) << 3) | ((e & 2) << 1) | ((e & 4) >> 1);
            v0[e] = __shfl(acc[0], r,     64);
            v1[e] = __shfl(acc[0], r + 1, 64);
        }
        if (lane == 0) {
            emit_token(v0, t0,     out, &cnt);
            emit_token(v1, t0 + 1, out, &cnt);
        }
    }

    // block histogram: tiny LDS reduce, then one atomic per expert per block
    if (lane == 0) {
#pragma unroll
        for (int e = 0; e < NEXP; ++e) {
            const unsigned c = (cnt >> (4 * e)) & 0xFu;
            if (c) atomicAdd(&h[e], (float)c);
        }
    }
    __syncthreads();
    if (tid < NEXP) atomicAdd(&out[HIST_OFF + tid], h[tid]);
}

extern "C" void kernel_launch(void* const* d_in, const int* in_sizes, int n_in,
                              void* d_out, int out_size, void* d_ws, size_t ws_size,
                              hipStream_t stream) {
    const float* x = (const float*)d_in[0];
    const float* W = (const float*)d_in[1];
    float* out = (float*)d_out;

    zero_hist_kernel<<<1, 64, 0, stream>>>(out);
    router_kernel<<<GRID, BLOCK, 0, stream>>>(x, W, out);
}

// Round 9
// 64.075 us; speedup vs baseline: 4.9901x; 4.9901x over previous
//
#include <hip/hip_runtime.h>
#include <hip/hip_bf16.h>
#include <math.h>

#define N_TOKENS 32768
#define HIDDEN   2048
#define NEXP     8
#define H4       (HIDDEN / 4)            // 512 float4 per row
#define BLOCK    512                     // 8 waves
#define WPB      (BLOCK / 64)
#define TPW      4                       // tokens per wave per group
#define GROUPS   2                       // token-groups per block (W staged once)
#define GRID     (N_TOKENS / (WPB * TPW * GROUPS))   // 512 blocks = 2/CU

#define SCORES_OFF 0
#define IDX_OFF    (N_TOKENS * 2)        // 65536
#define HIST_OFF   (N_TOKENS * 4)        // 131072

__global__ void zero_hist_kernel(float* out) {
    if (threadIdx.x < NEXP) out[HIST_OFF + threadIdx.x] = 0.0f;
}

// top-2 with lowest-index tie-break (strict >), matching jax.lax.top_k.
// cnt: packed 4-bit per-expert counters (max 8 tokens/wave -> fits).
__device__ __forceinline__ void emit_token(const double* acc, int t,
                                           float* __restrict__ out, unsigned* cnt) {
    double b1 = acc[0]; int i1 = 0;
    double b2 = -1.0e300; int i2 = 0;
#pragma unroll
    for (int e = 1; e < NEXP; ++e) {
        double v = acc[e];
        if (v > b1)      { b2 = b1; i2 = i1; b1 = v; i1 = e; }
        else if (v > b2) { b2 = v;  i2 = e; }
    }
    float d  = (float)(b2 - b1);
    float e1 = expf(d);
    float s0 = 1.0f / (1.0f + e1);

    float2 sc; sc.x = s0; sc.y = e1 * s0;
    float2 ix; ix.x = (float)i1; ix.y = (float)i2;
    *reinterpret_cast<float2*>(out + SCORES_OFF + 2 * t) = sc;
    *reinterpret_cast<float2*>(out + IDX_OFF    + 2 * t) = ix;

    *cnt += (1u << (4 * i1)) + (1u << (4 * i2));
}

// Round-7 structure, W amortized over 4 tokens/pass (halves LDS W duty).
// acc[32] f64 = 64 VGPR -> 128-reg budget via __launch_bounds__(512,4).
// ALL inner loops fully unrolled: static indices only (r8's unroll-1 e-loop
// sent acc[] to scratch -> 670 MB spill; rule #20).
// Per-token sums bit-identical to r7: same 8-elem f32 groups, same f64
// butterfly tree (masks 1,2,4,8,16,32 in order).
__global__ __launch_bounds__(BLOCK, 4) void router_kernel(
        const float* __restrict__ x, const float* __restrict__ W,
        float* __restrict__ out) {
    __shared__ float4 wlds[NEXP * H4];   // 64 KiB, staged once per block

    const int tid = threadIdx.x;
    const float4* Wv = reinterpret_cast<const float4*>(W);
#pragma unroll
    for (int i = 0; i < (NEXP * H4) / BLOCK; ++i)
        wlds[tid + i * BLOCK] = Wv[tid + i * BLOCK];
    __syncthreads();

    const int wave = tid >> 6;
    const int lane = tid & 63;

    unsigned cnt = 0;

#pragma unroll 1
    for (int g = 0; g < GROUPS; ++g) {
        const int t0 = (blockIdx.x * GROUPS + g) * (WPB * TPW) + wave * TPW;
        const float4* xa = reinterpret_cast<const float4*>(x) + (size_t)t0 * H4;
        const float4* xb = xa + H4;
        const float4* xc = xb + H4;
        const float4* xd = xc + H4;

        // acc[t*8+e], t in {0..3} = tokens a..d
        double acc[32];
#pragma unroll
        for (int i = 0; i < 32; ++i) acc[i] = 0.0;

#pragma unroll 1
        for (int k = 0; k < 8; k += 2) {     // 4 iterations, 8-elem dot groups
            const float4 a0 = xa[lane + k * 64], a1 = xa[lane + (k + 1) * 64];
            const float4 b0 = xb[lane + k * 64], b1 = xb[lane + (k + 1) * 64];
            const float4 c0 = xc[lane + k * 64], c1 = xc[lane + (k + 1) * 64];
            const float4 d0 = xd[lane + k * 64], d1 = xd[lane + (k + 1) * 64];
#pragma unroll
            for (int e = 0; e < NEXP; ++e) {
                const float4 w0 = wlds[e * H4 + lane + k * 64];
                const float4 w1 = wlds[e * H4 + lane + (k + 1) * 64];
                float sa = w0.x * a0.x;
                sa = fmaf(w0.y, a0.y, sa); sa = fmaf(w0.z, a0.z, sa); sa = fmaf(w0.w, a0.w, sa);
                sa = fmaf(w1.x, a1.x, sa); sa = fmaf(w1.y, a1.y, sa);
                sa = fmaf(w1.z, a1.z, sa); sa = fmaf(w1.w, a1.w, sa);
                float sb = w0.x * b0.x;
                sb = fmaf(w0.y, b0.y, sb); sb = fmaf(w0.z, b0.z, sb); sb = fmaf(w0.w, b0.w, sb);
                sb = fmaf(w1.x, b1.x, sb); sb = fmaf(w1.y, b1.y, sb);
                sb = fmaf(w1.z, b1.z, sb); sb = fmaf(w1.w, b1.w, sb);
                float sc = w0.x * c0.x;
                sc = fmaf(w0.y, c0.y, sc); sc = fmaf(w0.z, c0.z, sc); sc = fmaf(w0.w, c0.w, sc);
                sc = fmaf(w1.x, c1.x, sc); sc = fmaf(w1.y, c1.y, sc);
                sc = fmaf(w1.z, c1.z, sc); sc = fmaf(w1.w, c1.w, sc);
                float sd = w0.x * d0.x;
                sd = fmaf(w0.y, d0.y, sd); sd = fmaf(w0.z, d0.z, sd); sd = fmaf(w0.w, d0.w, sd);
                sd = fmaf(w1.x, d1.x, sd); sd = fmaf(w1.y, d1.y, sd);
                sd = fmaf(w1.z, d1.z, sd); sd = fmaf(w1.w, d1.w, sd);
                acc[e]      += (double)sa;   // one f64 accumulate per 8 elems
                acc[8 + e]  += (double)sb;
                acc[16 + e] += (double)sc;
                acc[24 + e] += (double)sd;
            }
        }

        // reduce-scatter butterfly, 32 values: masks 1,2,4,8,16 halve
        // 32/lane -> 1, then 32 finishes. Value j ends at lane bitrev5(j).
        // Same pairing/order as verified r6/r7 scheme (one more step).
        {
            const bool u1 = lane & 1;
#pragma unroll
            for (int i = 0; i < 16; ++i) {
                double send = u1 ? acc[i] : acc[16 + i];
                double got  = __shfl_xor(send, 1, 64);
                acc[i] = (u1 ? acc[16 + i] : acc[i]) + got;
            }
            const bool u2 = lane & 2;
#pragma unroll
            for (int i = 0; i < 8; ++i) {
                double send = u2 ? acc[i] : acc[8 + i];
                double got  = __shfl_xor(send, 2, 64);
                acc[i] = (u2 ? acc[8 + i] : acc[i]) + got;
            }
            const bool u4 = lane & 4;
#pragma unroll
            for (int i = 0; i < 4; ++i) {
                double send = u4 ? acc[i] : acc[4 + i];
                double got  = __shfl_xor(send, 4, 64);
                acc[i] = (u4 ? acc[4 + i] : acc[i]) + got;
            }
            const bool u8 = lane & 8;
#pragma unroll
            for (int i = 0; i < 2; ++i) {
                double send = u8 ? acc[i] : acc[2 + i];
                double got  = __shfl_xor(send, 8, 64);
                acc[i] = (u8 ? acc[2 + i] : acc[i]) + got;
            }
            const bool u16 = lane & 16;
            {
                double send = u16 ? acc[0] : acc[1];
                double got  = __shfl_xor(send, 16, 64);
                acc[0] = (u16 ? acc[1] : acc[0]) + got;
            }
            acc[0] += __shfl_xor(acc[0], 32, 64);
        }

        // gather + emit one token at a time (keeps live regs low).
        // value j = t*8+e at lane r: bit0=t>>1, bit1=t&1, bit2=e>>2,
        // bit3=(e>>1)&1, bit4=e&1.
#pragma unroll
        for (int t = 0; t < TPW; ++t) {
            double v[NEXP];
#pragma unroll
            for (int e = 0; e < NEXP; ++e) {
                const int r = ((t >> 1) & 1) | ((t & 1) << 1) | (((e >> 2) & 1) << 2)
                            | (((e >> 1) & 1) << 3) | ((e & 1) << 4);
                v[e] = __shfl(acc[0], r, 64);
            }
            if (lane == 0) emit_token(v, t0 + t, out, &cnt);
        }
    }

    // block histogram: reuse wlds as scratch after all waves done with W
    __syncthreads();
    float* h = reinterpret_cast<float*>(wlds);
    if (tid < NEXP) h[tid] = 0.0f;
    __syncthreads();
    if (lane == 0) {
#pragma unroll
        for (int e = 0; e < NEXP; ++e) {
            const unsigned c = (cnt >> (4 * e)) & 0xFu;
            if (c) atomicAdd(&h[e], (float)c);
        }
    }
    __syncthreads();
    if (tid < NEXP) atomicAdd(&out[HIST_OFF + tid], h[tid]);
}

extern "C" void kernel_launch(void* const* d_in, const int* in_sizes, int n_in,
                              void* d_out, int out_size, void* d_ws, size_t ws_size,
                              hipStream_t stream) {
    const float* x = (const float*)d_in[0];
    const float* W = (const float*)d_in[1];
    float* out = (float*)d_out;

    zero_hist_kernel<<<1, 64, 0, stream>>>(out);
    router_kernel<<<GRID, BLOCK, 0, stream>>>(x, W, out);
}

// Round 10
// 62.839 us; speedup vs baseline: 5.0882x; 1.0197x over previous
//
#include <hip/hip_runtime.h>
#include <hip/hip_bf16.h>
#include <math.h>

#define N_TOKENS 32768
#define HIDDEN   2048
#define NEXP     8
#define H4       (HIDDEN / 4)            // 512 float4 per row
#define BLOCK    1024                    // 16 waves
#define WPB      (BLOCK / 64)
#define TOK_PER_WAVE 4
#define GRID     (N_TOKENS / (WPB * TOK_PER_WAVE))   // 512 blocks = 2/CU

#define SCORES_OFF 0
#define IDX_OFF    (N_TOKENS * 2)        // 65536
#define HIST_OFF   (N_TOKENS * 4)        // 131072

// native vector alias: __builtin_nontemporal_load needs a real vector type
typedef float v4f __attribute__((ext_vector_type(4)));

__global__ void zero_hist_kernel(float* out) {
    if (threadIdx.x < NEXP) out[HIST_OFF + threadIdx.x] = 0.0f;
}

// top-2 with lowest-index tie-break (strict >), matching jax.lax.top_k.
// cnt: packed 4-bit per-expert counters (max 4 tokens/wave -> fits).
__device__ __forceinline__ void emit_token(const double* acc, int t,
                                           float* __restrict__ out, unsigned* cnt) {
    double b1 = acc[0]; int i1 = 0;
    double b2 = -1.0e300; int i2 = 0;
#pragma unroll
    for (int e = 1; e < NEXP; ++e) {
        double v = acc[e];
        if (v > b1)      { b2 = b1; i2 = i1; b1 = v; i1 = e; }
        else if (v > b2) { b2 = v;  i2 = e; }
    }
    float d  = (float)(b2 - b1);
    float e1 = expf(d);
    float s0 = 1.0f / (1.0f + e1);

    float2 sc; sc.x = s0; sc.y = e1 * s0;
    float2 ix; ix.x = (float)i1; ix.y = (float)i2;
    *reinterpret_cast<float2*>(out + SCORES_OFF + 2 * t) = sc;
    *reinterpret_cast<float2*>(out + IDX_OFF    + 2 * t) = ix;

    *cnt += (1u << (4 * i1)) + (1u << (4 * i2));
}

// Round-7 structure (best: 62.4 us) + non-temporal x loads:
// x is read exactly once (zero reuse) -> nt keeps it out of L2's
// replacement set, so the hot 64 KB W stays L2-resident across blocks,
// killing the ~35 MB W re-fetch seen in r7's FETCH_SIZE (292 vs 256 MB).
// Numerics byte-identical to r7 (same dot groups, same butterfly order).
__global__ __launch_bounds__(BLOCK, 4) void router_kernel(
        const float* __restrict__ x, const float* __restrict__ W,
        float* __restrict__ out) {
    __shared__ float4 wlds[NEXP * H4];   // 64 KiB

    const int tid = threadIdx.x;
    const float4* Wv = reinterpret_cast<const float4*>(W);
#pragma unroll
    for (int i = 0; i < (NEXP * H4) / BLOCK; ++i)
        wlds[tid + i * BLOCK] = Wv[tid + i * BLOCK];   // normal loads: keep W cached
    __syncthreads();

    const int wave = tid >> 6;
    const int lane = tid & 63;
    const int gw   = blockIdx.x * WPB + wave;

    unsigned cnt = 0;

#pragma unroll 1
    for (int p = 0; p < TOK_PER_WAVE / 2; ++p) {
        const int t0 = gw * TOK_PER_WAVE + 2 * p;
        const v4f* xa = reinterpret_cast<const v4f*>(x) + (size_t)t0 * H4;
        const v4f* xb = xa + H4;

        // acc[0..7] = token a, acc[8..15] = token b
        double acc[16];
#pragma unroll
        for (int e = 0; e < 16; ++e) acc[e] = 0.0;

#pragma unroll 1
        for (int k = 0; k < 8; k += 2) {     // 4 iterations, 8-elem dot groups
            const v4f a0 = __builtin_nontemporal_load(&xa[lane + k * 64]);
            const v4f a1 = __builtin_nontemporal_load(&xa[lane + (k + 1) * 64]);
            const v4f b0 = __builtin_nontemporal_load(&xb[lane + k * 64]);
            const v4f b1 = __builtin_nontemporal_load(&xb[lane + (k + 1) * 64]);
#pragma unroll
            for (int e = 0; e < NEXP; ++e) {
                const float4 w0 = wlds[e * H4 + lane + k * 64];
                float s0 = w0.x * a0.x;
                s0 = fmaf(w0.y, a0.y, s0); s0 = fmaf(w0.z, a0.z, s0); s0 = fmaf(w0.w, a0.w, s0);
                float s1 = w0.x * b0.x;
                s1 = fmaf(w0.y, b0.y, s1); s1 = fmaf(w0.z, b0.z, s1); s1 = fmaf(w0.w, b0.w, s1);
                const float4 w1 = wlds[e * H4 + lane + (k + 1) * 64];
                s0 = fmaf(w1.x, a1.x, s0); s0 = fmaf(w1.y, a1.y, s0);
                s0 = fmaf(w1.z, a1.z, s0); s0 = fmaf(w1.w, a1.w, s0);
                s1 = fmaf(w1.x, b1.x, s1); s1 = fmaf(w1.y, b1.y, s1);
                s1 = fmaf(w1.z, b1.z, s1); s1 = fmaf(w1.w, b1.w, s1);
                // one f64 accumulate per 8 elements
                acc[e]     += (double)s0;
                acc[8 + e] += (double)s1;
            }
        }

        // reduce-scatter butterfly (verified r6/r7): masks 1,2,4,8 halve
        // 16 values/lane -> 1, then 16,32 finish. Bit-identical totals to
        // the full butterfly (same pairing, commutative adds).
        {
            const bool u1 = lane & 1;
#pragma unroll
            for (int i = 0; i < 8; ++i) {
                double send = u1 ? acc[i] : acc[8 + i];
                double got  = __shfl_xor(send, 1, 64);
                acc[i] = (u1 ? acc[8 + i] : acc[i]) + got;
            }
            const bool u2 = lane & 2;
#pragma unroll
            for (int i = 0; i < 4; ++i) {
                double send = u2 ? acc[i] : acc[4 + i];
                double got  = __shfl_xor(send, 2, 64);
                acc[i] = (u2 ? acc[4 + i] : acc[i]) + got;
            }
            const bool u4 = lane & 4;
#pragma unroll
            for (int i = 0; i < 2; ++i) {
                double send = u4 ? acc[i] : acc[2 + i];
                double got  = __shfl_xor(send, 4, 64);
                acc[i] = (u4 ? acc[2 + i] : acc[i]) + got;
            }
            const bool u8 = lane & 8;
            {
                double send = u8 ? acc[0] : acc[1];
                double got  = __shfl_xor(send, 8, 64);
                acc[0] = (u8 ? acc[1] : acc[0]) + got;
            }
            acc[0] += __shfl_xor(acc[0], 16, 64);
            acc[0] += __shfl_xor(acc[0], 32, 64);
        }
        // value j sits at lane bitrev4(j): token a (j=e) at r, token b at r+1
        double v0[NEXP], v1[NEXP];
#pragma unroll
        for (int e = 0; e < NEXP; ++e) {
            const int r = ((e & 1) << 3) | ((e & 2) << 1) | ((e & 4) >> 1);
            v0[e] = __shfl(acc[0], r,     64);
            v1[e] = __shfl(acc[0], r + 1, 64);
        }
        if (lane == 0) {
            emit_token(v0, t0,     out, &cnt);
            emit_token(v1, t0 + 1, out, &cnt);
        }
    }

    // block histogram: reuse wlds as scratch after all waves done with W
    __syncthreads();
    float* h = reinterpret_cast<float*>(wlds);
    if (tid < NEXP) h[tid] = 0.0f;
    __syncthreads();
    if (lane == 0) {
#pragma unroll
        for (int e = 0; e < NEXP; ++e) {
            const unsigned c = (cnt >> (4 * e)) & 0xFu;
            if (c) atomicAdd(&h[e], (float)c);
        }
    }
    __syncthreads();
    if (tid < NEXP) atomicAdd(&out[HIST_OFF + tid], h[tid]);
}

extern "C" void kernel_launch(void* const* d_in, const int* in_sizes, int n_in,
                              void* d_out, int out_size, void* d_ws, size_t ws_size,
                              hipStream_t stream) {
    const float* x = (const float*)d_in[0];
    const float* W = (const float*)d_in[1];
    float* out = (float*)d_out;

    zero_hist_kernel<<<1, 64, 0, stream>>>(out);
    router_kernel<<<GRID, BLOCK, 0, stream>>>(x, W, out);
}